// Round 4
// baseline (557.651 us; speedup 1.0000x reference)
//
#include <hip/hip_runtime.h>

#define N_DIM 4
#define A_DIM 512
#define C_DIM 19
#define HW    16384            // 128*128
#define HIST_STRIDE 39         // 19 sum + 19 sq + 1 trash; odd => full bank spread
#define A_PAD 516              // keeps 16B row alignment, breaks pow2 bank aliasing
#define CA    (C_DIM * A_DIM)  // 9728

// ---------------------------------------------------------------------------
// Kernel 1: per-class sum/sumsq via per-THREAD private LDS histograms
// (ds_add_f32, zero address collisions). One block per (n,a). Blocks with a==0
// also produce label counts. Writes exclusive partial slots -> no memset.
// ---------------------------------------------------------------------------
__global__ __launch_bounds__(256) void reduce_kernel(const float* __restrict__ feat,
                                                     const int*   __restrict__ labels,
                                                     float* __restrict__ gsum_part,
                                                     float* __restrict__ gsq_part,
                                                     float* __restrict__ gcnt_part) {
    const int b = blockIdx.x;
    const int n = b >> 9;                 // / A_DIM
    const int a = b & (A_DIM - 1);
    const float4* f4 = (const float4*)(feat + ((size_t)(n * A_DIM + a)) * HW);
    const int4*   l4 = (const int4*)(labels + n * HW);

    __shared__ float hist[256 * HIST_STRIDE];   // 39936 B
    __shared__ float s_cnt[4][20];              // +320 B -> 40256 <= 40960 (4 blk/CU)

    const int tid = threadIdx.x;
    float* h = hist + tid * HIST_STRIDE;
    #pragma unroll
    for (int j = 0; j < HIST_STRIDE; ++j) h[j] = 0.f;

    const bool do_cnt = (a == 0);
    float cnt[C_DIM];
    #pragma unroll
    for (int c = 0; c < C_DIM; ++c) cnt[c] = 0.f;

    float4 f  = f4[tid];
    int4   lb = l4[tid];
    for (int ii = 0; ii < 16; ++ii) {
        float4 fc = f; int4 lc = lb;
        if (ii < 15) { f = f4[tid + (ii + 1) * 256]; lb = l4[tid + (ii + 1) * 256]; }
        { int l = lc.x; bool v = (unsigned)l < 19u; int as = v ? l : 38, aq = v ? l + 19 : 38;
          atomicAdd(&h[as], fc.x); atomicAdd(&h[aq], fc.x * fc.x); }
        { int l = lc.y; bool v = (unsigned)l < 19u; int as = v ? l : 38, aq = v ? l + 19 : 38;
          atomicAdd(&h[as], fc.y); atomicAdd(&h[aq], fc.y * fc.y); }
        { int l = lc.z; bool v = (unsigned)l < 19u; int as = v ? l : 38, aq = v ? l + 19 : 38;
          atomicAdd(&h[as], fc.z); atomicAdd(&h[aq], fc.z * fc.z); }
        { int l = lc.w; bool v = (unsigned)l < 19u; int as = v ? l : 38, aq = v ? l + 19 : 38;
          atomicAdd(&h[as], fc.w); atomicAdd(&h[aq], fc.w * fc.w); }
        if (do_cnt) {
            #pragma unroll
            for (int c = 0; c < C_DIM; ++c) {
                cnt[c] += ((lc.x == c) ? 1.f : 0.f) + ((lc.y == c) ? 1.f : 0.f)
                        + ((lc.z == c) ? 1.f : 0.f) + ((lc.w == c) ? 1.f : 0.f);
            }
        }
    }

    if (do_cnt) {
        #pragma unroll
        for (int c = 0; c < C_DIM; ++c) {
            float x = cnt[c];
            #pragma unroll
            for (int off = 32; off >= 1; off >>= 1) x += __shfl_xor(x, off);
            if ((tid & 63) == 0) s_cnt[tid >> 6][c] = x;
        }
    }
    __syncthreads();

    // columns 0..18 = sums, 19..37 = sumsq; threads 0..37 reduce 256 copies each
    if (tid < 38) {
        float a0 = 0.f, a1 = 0.f, a2 = 0.f, a3 = 0.f;
        for (int u = 0; u < 256; u += 4) {
            a0 += hist[(u    ) * HIST_STRIDE + tid];
            a1 += hist[(u + 1) * HIST_STRIDE + tid];
            a2 += hist[(u + 2) * HIST_STRIDE + tid];
            a3 += hist[(u + 3) * HIST_STRIDE + tid];
        }
        float acc = (a0 + a1) + (a2 + a3);
        if (tid < C_DIM) gsum_part[(n * C_DIM + tid) * A_DIM + a] = acc;
        else             gsq_part[(n * C_DIM + (tid - C_DIM)) * A_DIM + a] = acc;
    }
    if (do_cnt && tid < C_DIM)
        gcnt_part[n * 32 + tid] = s_cnt[0][tid] + s_cnt[1][tid] + s_cnt[2][tid] + s_cnt[3][tid];
}

// ---------------------------------------------------------------------------
// Kernel 2 (fused): finalize cov -> S[19][19] table (redundant per block,
// cheap) -> apply. 512 blocks x 256 threads, ~80KB LDS (2 blocks/CU).
// ---------------------------------------------------------------------------
__global__ __launch_bounds__(256) void fused_kernel(const float* __restrict__ gsum_part,
                                                    const float* __restrict__ gsq_part,
                                                    const float* __restrict__ gcnt_part,
                                                    const float* __restrict__ CoV,
                                                    const float* __restrict__ Ave,
                                                    const float* __restrict__ Amount,
                                                    const float* __restrict__ weight,
                                                    const float* __restrict__ ratio_p,
                                                    const float* __restrict__ y,
                                                    const int*   __restrict__ labels,
                                                    float* __restrict__ out) {
    alignas(16) __shared__ float s_cov[C_DIM][A_PAD];
    alignas(16) __shared__ float s_w[C_DIM][A_PAD];
    __shared__ float s_S[C_DIM * 20];
    __shared__ float s_wcv[C_DIM];
    __shared__ float s_inv[C_DIM];

    const int tid = threadIdx.x;
    if (tid < C_DIM) {
        float cn = gcnt_part[tid] + gcnt_part[32 + tid] + gcnt_part[64 + tid] + gcnt_part[96 + tid];
        float cs = (cn == 0.f) ? 1.f : cn;
        float denom = cn + Amount[tid];
        s_wcv[tid] = (denom == 0.f) ? 0.f : cn / denom;
        s_inv[tid] = 1.f / cs;
    }
    __syncthreads();

    // stage B: cov + weight into LDS (vectorized, 10 iters)
    for (int i4 = tid; i4 < CA / 4; i4 += 256) {
        const int c   = i4 >> 7;          // /128
        const int aa4 = i4 & 127;
        float4 s0 = ((const float4*)gsum_part)[i4];
        float4 s1 = ((const float4*)gsum_part)[i4 + CA / 4];
        float4 s2 = ((const float4*)gsum_part)[i4 + 2 * (CA / 4)];
        float4 s3 = ((const float4*)gsum_part)[i4 + 3 * (CA / 4)];
        float4 q0 = ((const float4*)gsq_part)[i4];
        float4 q1 = ((const float4*)gsq_part)[i4 + CA / 4];
        float4 q2 = ((const float4*)gsq_part)[i4 + 2 * (CA / 4)];
        float4 q3 = ((const float4*)gsq_part)[i4 + 3 * (CA / 4)];
        float4 cvv = ((const float4*)CoV)[i4];
        float4 avv = ((const float4*)Ave)[i4];
        float4 wv  = ((const float4*)weight)[i4];
        const float inv = s_inv[c], wcv = s_wcv[c], om = 1.f - wcv;
        float4 res;
        {
            float sm = s0.x + s1.x + s2.x + s3.x, sq = q0.x + q1.x + q2.x + q3.x;
            float ave = sm * inv, var = (sq - sm * ave) * inv, d = avv.x - ave;
            res.x = cvv.x * om + var * wcv + wcv * om * d * d;
        }
        {
            float sm = s0.y + s1.y + s2.y + s3.y, sq = q0.y + q1.y + q2.y + q3.y;
            float ave = sm * inv, var = (sq - sm * ave) * inv, d = avv.y - ave;
            res.y = cvv.y * om + var * wcv + wcv * om * d * d;
        }
        {
            float sm = s0.z + s1.z + s2.z + s3.z, sq = q0.z + q1.z + q2.z + q3.z;
            float ave = sm * inv, var = (sq - sm * ave) * inv, d = avv.z - ave;
            res.z = cvv.z * om + var * wcv + wcv * om * d * d;
        }
        {
            float sm = s0.w + s1.w + s2.w + s3.w, sq = q0.w + q1.w + q2.w + q3.w;
            float ave = sm * inv, var = (sq - sm * ave) * inv, d = avv.w - ave;
            res.w = cvv.w * om + var * wcv + wcv * om * d * d;
        }
        *(float4*)&s_cov[c][aa4 * 4] = res;
        *(float4*)&s_w[c][aa4 * 4]   = wv;
    }
    __syncthreads();

    // stage C: S[k][c] = ratio * sum_a cov[k][a]*(W[c][a]-W[k][a])^2
    // wave wv owns k = 5*wv..5*wv+4; lane -> (c = lane%19, rep = lane/19)
    {
        const float ratio = *ratio_p;
        const int lane = tid & 63;
        const int wv   = tid >> 6;
        const int rep  = lane / C_DIM;       // 0..2 active, 3 idle
        const int c    = lane % C_DIM;
        const int kbase = wv * 5;
        float acc[5];
        #pragma unroll
        for (int kk = 0; kk < 5; ++kk) acc[kk] = 0.f;
        for (int j = 0; j < 43; ++j) {
            const int a4 = rep + 3 * j;
            if (rep < 3 && a4 < 128) {
                float4 wc = *(const float4*)&s_w[c][a4 * 4];
                #pragma unroll
                for (int kk = 0; kk < 5; ++kk) {
                    int k = kbase + kk; if (k > 18) k = 18;   // clamp; result discarded
                    float4 cv = *(const float4*)&s_cov[k][a4 * 4];
                    float4 wk = *(const float4*)&s_w[k][a4 * 4];
                    float dx = wc.x - wk.x, dy = wc.y - wk.y;
                    float dz = wc.z - wk.z, dw = wc.w - wk.w;
                    acc[kk] = fmaf(cv.x, dx * dx, acc[kk]);
                    acc[kk] = fmaf(cv.y, dy * dy, acc[kk]);
                    acc[kk] = fmaf(cv.z, dz * dz, acc[kk]);
                    acc[kk] = fmaf(cv.w, dw * dw, acc[kk]);
                }
            }
        }
        #pragma unroll
        for (int kk = 0; kk < 5; ++kk) {
            const int k = kbase + kk;
            float v1 = __shfl(acc[kk], lane + 19);
            float v2 = __shfl(acc[kk], lane + 38);
            if (lane < C_DIM && k < C_DIM) s_S[k * 20 + lane] = ratio * (acc[kk] + v1 + v2);
        }
    }
    __syncthreads();

    // stage D: apply
    const int total4 = N_DIM * C_DIM * (HW / 4);   // 311296
    const int per_n  = C_DIM * (HW / 4);           // 77824
    for (int g = blockIdx.x * 256 + tid; g < total4; g += (int)gridDim.x * 256) {
        const int n   = g / per_n;
        const int rem = g - n * per_n;
        const int c   = rem >> 12;                 // /4096
        const int hw4 = rem & 4095;
        float4 yv = ((const float4*)y)[g];
        int4 lbv = ((const int4*)(labels + n * HW))[hw4];
        float4 r;
        { int l = lbv.x; bool v = (l != 255); int lu = ((unsigned)l < 19u) ? l : 0;
          r.x = yv.x + (v ? 0.5f * s_S[lu * 20 + c] : 0.f); }
        { int l = lbv.y; bool v = (l != 255); int lu = ((unsigned)l < 19u) ? l : 0;
          r.y = yv.y + (v ? 0.5f * s_S[lu * 20 + c] : 0.f); }
        { int l = lbv.z; bool v = (l != 255); int lu = ((unsigned)l < 19u) ? l : 0;
          r.z = yv.z + (v ? 0.5f * s_S[lu * 20 + c] : 0.f); }
        { int l = lbv.w; bool v = (l != 255); int lu = ((unsigned)l < 19u) ? l : 0;
          r.w = yv.w + (v ? 0.5f * s_S[lu * 20 + c] : 0.f); }
        ((float4*)out)[g] = r;
    }
}

// ---------------------------------------------------------------------------
extern "C" void kernel_launch(void* const* d_in, const int* in_sizes, int n_in,
                              void* d_out, int out_size, void* d_ws, size_t ws_size,
                              hipStream_t stream) {
    const float* feat   = (const float*)d_in[0];   // [N,A,H,W]
    const float* y      = (const float*)d_in[1];   // [N,C,H,W]
    const int*   labels = (const int*)d_in[2];     // [N,1,H,W] int32
    const float* weight = (const float*)d_in[3];   // [C,A]
    const float* CoV    = (const float*)d_in[4];   // [C,A]
    const float* Ave    = (const float*)d_in[5];   // [C,A]
    const float* Amount = (const float*)d_in[6];   // [C]
    const float* ratio  = (const float*)d_in[7];   // scalar

    float* out       = (float*)d_out;
    float* ws        = (float*)d_ws;
    float* gsum_part = ws;                 // [4][19][512]
    float* gsq_part  = ws + 4 * CA;        // [4][19][512]
    float* gcnt_part = ws + 8 * CA;        // [4][32]

    reduce_kernel<<<N_DIM * A_DIM, 256, 0, stream>>>(feat, labels, gsum_part, gsq_part, gcnt_part);
    fused_kernel<<<512, 256, 0, stream>>>(gsum_part, gsq_part, gcnt_part, CoV, Ave, Amount,
                                          weight, ratio, y, labels, out);
}

// Round 5
// 240.684 us; speedup vs baseline: 2.3169x; 2.3169x over previous
//
#include <hip/hip_runtime.h>

#define N_DIM 4
#define A_DIM 512
#define C_DIM 19
#define HW    16384            // 128*128
#define CA    (C_DIM * A_DIM)  // 9728
#define A_PAD 516              // keeps 16B row alignment, breaks pow2 bank aliasing

// ---------------------------------------------------------------------------
// Kernel 1: per-class sum/sumsq via per-THREAD private LDS stripes with plain
// read-modify-write (NO atomics — ds_add_f32 measured ~224cyc/instr in r4).
// Each thread owns 19 float2 (sum,sq). One block per (n,a). a==0 blocks also
// count labels via ballot/popcount on the scalar pipe.
// ---------------------------------------------------------------------------
__global__ __launch_bounds__(256) void reduce_kernel(const float* __restrict__ feat,
                                                     const int*   __restrict__ labels,
                                                     float* __restrict__ gsum_part,
                                                     float* __restrict__ gsq_part,
                                                     float* __restrict__ gcnt_part) {
    const int b = blockIdx.x;
    const int n = b >> 9;                 // / A_DIM
    const int a = b & (A_DIM - 1);
    const float4* f4 = (const float4*)(feat + ((size_t)(n * A_DIM + a)) * HW);
    const int4*   l4 = (const int4*)(labels + n * HW);

    __shared__ float2 hist[256 * C_DIM];   // 38912 B
    __shared__ float2 s_part[4][C_DIM];    // 608 B
    __shared__ float  s_cnt[4][C_DIM];     // 304 B  -> total < 40KB => 4 blk/CU

    const int tid = threadIdx.x;
    float2* h = hist + tid * C_DIM;
    #pragma unroll
    for (int j = 0; j < C_DIM; ++j) h[j] = make_float2(0.f, 0.f);
    // no barrier needed: each thread touches only its own stripe until the tail

    const bool do_cnt = (a == 0);
    unsigned cnts[C_DIM];
    #pragma unroll
    for (int c = 0; c < C_DIM; ++c) cnts[c] = 0u;

#define ACC(FF, LL) { \
        int l_ = (LL); bool v_ = ((unsigned)l_ < 19u); \
        int p_ = v_ ? l_ : 0; float fm_ = v_ ? (FF) : 0.f; \
        float2 hv_ = h[p_]; hv_.x += fm_; hv_.y = fmaf(fm_, fm_, hv_.y); h[p_] = hv_; }

    for (int ii = 0; ii < 16; ++ii) {
        float4 f  = f4[tid + ii * 256];
        int4   lb = l4[tid + ii * 256];
        ACC(f.x, lb.x);
        ACC(f.y, lb.y);
        ACC(f.z, lb.z);
        ACC(f.w, lb.w);
        if (do_cnt) {
            #pragma unroll
            for (int c = 0; c < C_DIM; ++c) {
                cnts[c] += __popcll(__ballot(lb.x == c)) + __popcll(__ballot(lb.y == c))
                         + __popcll(__ballot(lb.z == c)) + __popcll(__ballot(lb.w == c));
            }
        }
    }
#undef ACC

    if (do_cnt && (tid & 63) == 0) {
        const int w = tid >> 6;
        #pragma unroll
        for (int c = 0; c < C_DIM; ++c) s_cnt[w][c] = (float)cnts[c];
    }
    __syncthreads();

    // reduce the 256 stripes: 76 threads, each sums 64 stripes for one class
    if (tid < 4 * C_DIM) {
        const int c = tid % C_DIM;
        const int g = tid / C_DIM;
        float sx = 0.f, sq = 0.f;
        for (int u = g * 64; u < g * 64 + 64; ++u) {
            float2 v = hist[u * C_DIM + c];
            sx += v.x; sq += v.y;
        }
        s_part[g][c] = make_float2(sx, sq);
    }
    __syncthreads();

    if (tid < C_DIM) {
        float2 p0 = s_part[0][tid], p1 = s_part[1][tid];
        float2 p2 = s_part[2][tid], p3 = s_part[3][tid];
        gsum_part[(n * C_DIM + tid) * A_DIM + a] = (p0.x + p1.x) + (p2.x + p3.x);
        gsq_part [(n * C_DIM + tid) * A_DIM + a] = (p0.y + p1.y) + (p2.y + p3.y);
        if (do_cnt)
            gcnt_part[n * 32 + tid] = s_cnt[0][tid] + s_cnt[1][tid] + s_cnt[2][tid] + s_cnt[3][tid];
    }
}

// ---------------------------------------------------------------------------
// Kernel 2 (fused): finalize cov -> S[19][19] table (redundant per block,
// cheap) -> apply. 512 blocks x 256 threads.
// ---------------------------------------------------------------------------
__global__ __launch_bounds__(256) void fused_kernel(const float* __restrict__ gsum_part,
                                                    const float* __restrict__ gsq_part,
                                                    const float* __restrict__ gcnt_part,
                                                    const float* __restrict__ CoV,
                                                    const float* __restrict__ Ave,
                                                    const float* __restrict__ Amount,
                                                    const float* __restrict__ weight,
                                                    const float* __restrict__ ratio_p,
                                                    const float* __restrict__ y,
                                                    const int*   __restrict__ labels,
                                                    float* __restrict__ out) {
    alignas(16) __shared__ float s_cov[C_DIM][A_PAD];
    alignas(16) __shared__ float s_w[C_DIM][A_PAD];
    __shared__ float s_S[C_DIM * 20];
    __shared__ float s_wcv[C_DIM];
    __shared__ float s_inv[C_DIM];

    const int tid = threadIdx.x;
    if (tid < C_DIM) {
        float cn = gcnt_part[tid] + gcnt_part[32 + tid] + gcnt_part[64 + tid] + gcnt_part[96 + tid];
        float cs = (cn == 0.f) ? 1.f : cn;
        float denom = cn + Amount[tid];
        s_wcv[tid] = (denom == 0.f) ? 0.f : cn / denom;
        s_inv[tid] = 1.f / cs;
    }
    __syncthreads();

    // stage B: cov + weight into LDS
    for (int i4 = tid; i4 < CA / 4; i4 += 256) {
        const int c   = i4 >> 7;          // /128
        const int aa4 = i4 & 127;
        float4 s0 = ((const float4*)gsum_part)[i4];
        float4 s1 = ((const float4*)gsum_part)[i4 + CA / 4];
        float4 s2 = ((const float4*)gsum_part)[i4 + 2 * (CA / 4)];
        float4 s3 = ((const float4*)gsum_part)[i4 + 3 * (CA / 4)];
        float4 q0 = ((const float4*)gsq_part)[i4];
        float4 q1 = ((const float4*)gsq_part)[i4 + CA / 4];
        float4 q2 = ((const float4*)gsq_part)[i4 + 2 * (CA / 4)];
        float4 q3 = ((const float4*)gsq_part)[i4 + 3 * (CA / 4)];
        float4 cvv = ((const float4*)CoV)[i4];
        float4 avv = ((const float4*)Ave)[i4];
        float4 wv  = ((const float4*)weight)[i4];
        const float inv = s_inv[c], wcv = s_wcv[c], om = 1.f - wcv;
        float4 res;
        {
            float sm = s0.x + s1.x + s2.x + s3.x, sq = q0.x + q1.x + q2.x + q3.x;
            float ave = sm * inv, var = (sq - sm * ave) * inv, d = avv.x - ave;
            res.x = cvv.x * om + var * wcv + wcv * om * d * d;
        }
        {
            float sm = s0.y + s1.y + s2.y + s3.y, sq = q0.y + q1.y + q2.y + q3.y;
            float ave = sm * inv, var = (sq - sm * ave) * inv, d = avv.y - ave;
            res.y = cvv.y * om + var * wcv + wcv * om * d * d;
        }
        {
            float sm = s0.z + s1.z + s2.z + s3.z, sq = q0.z + q1.z + q2.z + q3.z;
            float ave = sm * inv, var = (sq - sm * ave) * inv, d = avv.z - ave;
            res.z = cvv.z * om + var * wcv + wcv * om * d * d;
        }
        {
            float sm = s0.w + s1.w + s2.w + s3.w, sq = q0.w + q1.w + q2.w + q3.w;
            float ave = sm * inv, var = (sq - sm * ave) * inv, d = avv.w - ave;
            res.w = cvv.w * om + var * wcv + wcv * om * d * d;
        }
        *(float4*)&s_cov[c][aa4 * 4] = res;
        *(float4*)&s_w[c][aa4 * 4]   = wv;
    }
    __syncthreads();

    // stage C: S[k][c] = ratio * sum_a cov[k][a]*(W[c][a]-W[k][a])^2
    {
        const float ratio = *ratio_p;
        const int lane = tid & 63;
        const int wv   = tid >> 6;
        const int rep  = lane / C_DIM;       // 0..2 active, 3 idle
        const int c    = lane % C_DIM;
        const int kbase = wv * 5;
        float acc[5];
        #pragma unroll
        for (int kk = 0; kk < 5; ++kk) acc[kk] = 0.f;
        for (int j = 0; j < 43; ++j) {
            const int a4 = rep + 3 * j;
            if (rep < 3 && a4 < 128) {
                float4 wc = *(const float4*)&s_w[c][a4 * 4];
                #pragma unroll
                for (int kk = 0; kk < 5; ++kk) {
                    int k = kbase + kk; if (k > 18) k = 18;   // clamp; result discarded
                    float4 cv = *(const float4*)&s_cov[k][a4 * 4];
                    float4 wk = *(const float4*)&s_w[k][a4 * 4];
                    float dx = wc.x - wk.x, dy = wc.y - wk.y;
                    float dz = wc.z - wk.z, dw = wc.w - wk.w;
                    acc[kk] = fmaf(cv.x, dx * dx, acc[kk]);
                    acc[kk] = fmaf(cv.y, dy * dy, acc[kk]);
                    acc[kk] = fmaf(cv.z, dz * dz, acc[kk]);
                    acc[kk] = fmaf(cv.w, dw * dw, acc[kk]);
                }
            }
        }
        #pragma unroll
        for (int kk = 0; kk < 5; ++kk) {
            const int k = kbase + kk;
            float v1 = __shfl(acc[kk], lane + 19);
            float v2 = __shfl(acc[kk], lane + 38);
            if (lane < C_DIM && k < C_DIM) s_S[k * 20 + lane] = ratio * (acc[kk] + v1 + v2);
        }
    }
    __syncthreads();

    // stage D: apply
    const int total4 = N_DIM * C_DIM * (HW / 4);   // 311296
    const int per_n  = C_DIM * (HW / 4);           // 77824
    for (int g = blockIdx.x * 256 + tid; g < total4; g += (int)gridDim.x * 256) {
        const int n   = g / per_n;
        const int rem = g - n * per_n;
        const int c   = rem >> 12;                 // /4096
        const int hw4 = rem & 4095;
        float4 yv = ((const float4*)y)[g];
        int4 lbv = ((const int4*)(labels + n * HW))[hw4];
        float4 r;
        { int l = lbv.x; bool v = (l != 255); int lu = ((unsigned)l < 19u) ? l : 0;
          r.x = yv.x + (v ? 0.5f * s_S[lu * 20 + c] : 0.f); }
        { int l = lbv.y; bool v = (l != 255); int lu = ((unsigned)l < 19u) ? l : 0;
          r.y = yv.y + (v ? 0.5f * s_S[lu * 20 + c] : 0.f); }
        { int l = lbv.z; bool v = (l != 255); int lu = ((unsigned)l < 19u) ? l : 0;
          r.z = yv.z + (v ? 0.5f * s_S[lu * 20 + c] : 0.f); }
        { int l = lbv.w; bool v = (l != 255); int lu = ((unsigned)l < 19u) ? l : 0;
          r.w = yv.w + (v ? 0.5f * s_S[lu * 20 + c] : 0.f); }
        ((float4*)out)[g] = r;
    }
}

// ---------------------------------------------------------------------------
extern "C" void kernel_launch(void* const* d_in, const int* in_sizes, int n_in,
                              void* d_out, int out_size, void* d_ws, size_t ws_size,
                              hipStream_t stream) {
    const float* feat   = (const float*)d_in[0];   // [N,A,H,W]
    const float* y      = (const float*)d_in[1];   // [N,C,H,W]
    const int*   labels = (const int*)d_in[2];     // [N,1,H,W] int32
    const float* weight = (const float*)d_in[3];   // [C,A]
    const float* CoV    = (const float*)d_in[4];   // [C,A]
    const float* Ave    = (const float*)d_in[5];   // [C,A]
    const float* Amount = (const float*)d_in[6];   // [C]
    const float* ratio  = (const float*)d_in[7];   // scalar

    float* out       = (float*)d_out;
    float* ws        = (float*)d_ws;
    float* gsum_part = ws;                 // [4][19][512]
    float* gsq_part  = ws + 4 * CA;        // [4][19][512]
    float* gcnt_part = ws + 8 * CA;        // [4][32]

    reduce_kernel<<<N_DIM * A_DIM, 256, 0, stream>>>(feat, labels, gsum_part, gsq_part, gcnt_part);
    fused_kernel<<<512, 256, 0, stream>>>(gsum_part, gsq_part, gcnt_part, CoV, Ave, Amount,
                                          weight, ratio, y, labels, out);
}

// Round 7
// 231.776 us; speedup vs baseline: 2.4060x; 1.0384x over previous
//
#include <hip/hip_runtime.h>

#define N_DIM 4
#define A_DIM 512
#define C_DIM 19
#define HW    16384            // 128*128
#define CA    (C_DIM * A_DIM)  // 9728
#define A_PAD 516              // keeps 16B row alignment, breaks pow2 bank aliasing

// ---------------------------------------------------------------------------
// Kernel 1: per-class sum/sumsq via per-THREAD private LDS stripes.
// v3: speculative batched reads + register alias-forwarding. The 4 reads of an
// iteration issue together (independent); intra-quad same-label increments are
// merged in VALU; write order (x,y,z,w) makes the last writer win with all
// increments included. Breaks the 120cyc-per-element dependent DS chain that
// made v2 latency-bound (~50us).
// ---------------------------------------------------------------------------
__global__ __launch_bounds__(256) void reduce_kernel(const float* __restrict__ feat,
                                                     const int*   __restrict__ labels,
                                                     float* __restrict__ gsum_part,
                                                     float* __restrict__ gsq_part,
                                                     float* __restrict__ gcnt_part) {
    const int b = blockIdx.x;
    const int n = b >> 9;                 // / A_DIM
    const int a = b & (A_DIM - 1);
    const float4* f4 = (const float4*)(feat + ((size_t)(n * A_DIM + a)) * HW);
    const int4*   l4 = (const int4*)(labels + n * HW);

    __shared__ float2 hist[256 * C_DIM];   // 38912 B
    __shared__ float2 s_part[4][C_DIM];    // 608 B
    __shared__ float  s_cnt[4][C_DIM];     // 304 B  -> total 39824 => 4 blk/CU

    const int tid = threadIdx.x;
    float2* h = hist + tid * C_DIM;
    #pragma unroll
    for (int j = 0; j < C_DIM; ++j) h[j] = make_float2(0.f, 0.f);
    // no barrier: each thread touches only its own stripe until the tail

    const bool do_cnt = (a == 0);
    unsigned cnts[C_DIM];
    #pragma unroll
    for (int c = 0; c < C_DIM; ++c) cnts[c] = 0u;

    float4 f  = f4[tid];
    int4   lb = l4[tid];
    for (int ii = 0; ii < 16; ++ii) {
        float4 fc = f; int4 lc = lb;
        if (ii < 15) { f = f4[tid + (ii + 1) * 256]; lb = l4[tid + (ii + 1) * 256]; }

        const int px = ((unsigned)lc.x < 19u) ? lc.x : 0;
        const int py = ((unsigned)lc.y < 19u) ? lc.y : 0;
        const int pz = ((unsigned)lc.z < 19u) ? lc.z : 0;
        const int pw = ((unsigned)lc.w < 19u) ? lc.w : 0;
        const float sx = ((unsigned)lc.x < 19u) ? fc.x : 0.f;
        const float sy = ((unsigned)lc.y < 19u) ? fc.y : 0.f;
        const float sz = ((unsigned)lc.z < 19u) ? fc.z : 0.f;
        const float sw = ((unsigned)lc.w < 19u) ? fc.w : 0.f;
        const float qx = sx * sx, qy = sy * sy, qz = sz * sz, qw = sw * sw;

        // speculative batched reads (may be stale w.r.t. aliasing quad members)
        float2 hx = h[px], hy = h[py], hz = h[pz], hw = h[pw];

        // alias-forwarding: v_j = stale_j + inc_j + sum of earlier aliased incs
        const bool eyx = (py == px);
        const bool ezx = (pz == px), ezy = (pz == py);
        const bool ewx = (pw == px), ewy = (pw == py), ewz = (pw == pz);

        float2 vx = make_float2(hx.x + sx, hx.y + qx);
        float2 vy = make_float2(hy.x + sy + (eyx ? sx : 0.f),
                                hy.y + qy + (eyx ? qx : 0.f));
        float2 vz = make_float2(hz.x + sz + (ezx ? sx : 0.f) + (ezy ? sy : 0.f),
                                hz.y + qz + (ezx ? qx : 0.f) + (ezy ? qy : 0.f));
        float2 vw = make_float2(hw.x + sw + (ewx ? sx : 0.f) + (ewy ? sy : 0.f) + (ewz ? sz : 0.f),
                                hw.y + qw + (ewx ? qx : 0.f) + (ewy ? qy : 0.f) + (ewz ? qz : 0.f));

        // same-address writes from one wave land in instruction order:
        // the last aliased writer carries all increments.
        h[px] = vx;
        h[py] = vy;
        h[pz] = vz;
        h[pw] = vw;

        if (do_cnt) {
            #pragma unroll
            for (int c = 0; c < C_DIM; ++c) {
                cnts[c] += __popcll(__ballot(lc.x == c)) + __popcll(__ballot(lc.y == c))
                         + __popcll(__ballot(lc.z == c)) + __popcll(__ballot(lc.w == c));
            }
        }
    }

    if (do_cnt && (tid & 63) == 0) {
        const int w = tid >> 6;
        #pragma unroll
        for (int c = 0; c < C_DIM; ++c) s_cnt[w][c] = (float)cnts[c];
    }
    __syncthreads();

    // reduce the 256 stripes: 76 threads, each sums 64 stripes for one class
    if (tid < 4 * C_DIM) {
        const int c = tid % C_DIM;
        const int g = tid / C_DIM;
        float sx = 0.f, sq = 0.f;
        for (int u = g * 64; u < g * 64 + 64; ++u) {
            float2 v = hist[u * C_DIM + c];
            sx += v.x; sq += v.y;
        }
        s_part[g][c] = make_float2(sx, sq);
    }
    __syncthreads();

    if (tid < C_DIM) {
        float2 p0 = s_part[0][tid], p1 = s_part[1][tid];
        float2 p2 = s_part[2][tid], p3 = s_part[3][tid];
        gsum_part[(n * C_DIM + tid) * A_DIM + a] = (p0.x + p1.x) + (p2.x + p3.x);
        gsq_part [(n * C_DIM + tid) * A_DIM + a] = (p0.y + p1.y) + (p2.y + p3.y);
        if (do_cnt)
            gcnt_part[n * 32 + tid] = s_cnt[0][tid] + s_cnt[1][tid] + s_cnt[2][tid] + s_cnt[3][tid];
    }
}

// ---------------------------------------------------------------------------
// Kernel 2 (fused): finalize cov -> S[19][19] table (redundant per block,
// cheap) -> apply. 512 blocks x 256 threads.
// ---------------------------------------------------------------------------
__global__ __launch_bounds__(256) void fused_kernel(const float* __restrict__ gsum_part,
                                                    const float* __restrict__ gsq_part,
                                                    const float* __restrict__ gcnt_part,
                                                    const float* __restrict__ CoV,
                                                    const float* __restrict__ Ave,
                                                    const float* __restrict__ Amount,
                                                    const float* __restrict__ weight,
                                                    const float* __restrict__ ratio_p,
                                                    const float* __restrict__ y,
                                                    const int*   __restrict__ labels,
                                                    float* __restrict__ out) {
    alignas(16) __shared__ float s_cov[C_DIM][A_PAD];
    alignas(16) __shared__ float s_w[C_DIM][A_PAD];
    __shared__ float s_S[C_DIM * 20];
    __shared__ float s_wcv[C_DIM];
    __shared__ float s_inv[C_DIM];

    const int tid = threadIdx.x;
    if (tid < C_DIM) {
        float cn = gcnt_part[tid] + gcnt_part[32 + tid] + gcnt_part[64 + tid] + gcnt_part[96 + tid];
        float cs = (cn == 0.f) ? 1.f : cn;
        float denom = cn + Amount[tid];
        s_wcv[tid] = (denom == 0.f) ? 0.f : cn / denom;
        s_inv[tid] = 1.f / cs;
    }
    __syncthreads();

    // stage B: cov + weight into LDS
    for (int i4 = tid; i4 < CA / 4; i4 += 256) {
        const int c   = i4 >> 7;          // /128
        const int aa4 = i4 & 127;
        float4 s0 = ((const float4*)gsum_part)[i4];
        float4 s1 = ((const float4*)gsum_part)[i4 + CA / 4];
        float4 s2 = ((const float4*)gsum_part)[i4 + 2 * (CA / 4)];
        float4 s3 = ((const float4*)gsum_part)[i4 + 3 * (CA / 4)];
        float4 q0 = ((const float4*)gsq_part)[i4];
        float4 q1 = ((const float4*)gsq_part)[i4 + CA / 4];
        float4 q2 = ((const float4*)gsq_part)[i4 + 2 * (CA / 4)];
        float4 q3 = ((const float4*)gsq_part)[i4 + 3 * (CA / 4)];
        float4 cvv = ((const float4*)CoV)[i4];
        float4 avv = ((const float4*)Ave)[i4];
        float4 wv  = ((const float4*)weight)[i4];
        const float inv = s_inv[c], wcv = s_wcv[c], om = 1.f - wcv;
        float4 res;
        {
            float sm = s0.x + s1.x + s2.x + s3.x, sq = q0.x + q1.x + q2.x + q3.x;
            float ave = sm * inv, var = (sq - sm * ave) * inv, d = avv.x - ave;
            res.x = cvv.x * om + var * wcv + wcv * om * d * d;
        }
        {
            float sm = s0.y + s1.y + s2.y + s3.y, sq = q0.y + q1.y + q2.y + q3.y;
            float ave = sm * inv, var = (sq - sm * ave) * inv, d = avv.y - ave;
            res.y = cvv.y * om + var * wcv + wcv * om * d * d;
        }
        {
            float sm = s0.z + s1.z + s2.z + s3.z, sq = q0.z + q1.z + q2.z + q3.z;
            float ave = sm * inv, var = (sq - sm * ave) * inv, d = avv.z - ave;
            res.z = cvv.z * om + var * wcv + wcv * om * d * d;
        }
        {
            float sm = s0.w + s1.w + s2.w + s3.w, sq = q0.w + q1.w + q2.w + q3.w;
            float ave = sm * inv, var = (sq - sm * ave) * inv, d = avv.w - ave;
            res.w = cvv.w * om + var * wcv + wcv * om * d * d;
        }
        *(float4*)&s_cov[c][aa4 * 4] = res;
        *(float4*)&s_w[c][aa4 * 4]   = wv;
    }
    __syncthreads();

    // stage C: S[k][c] = ratio * sum_a cov[k][a]*(W[c][a]-W[k][a])^2
    {
        const float ratio = *ratio_p;
        const int lane = tid & 63;
        const int wv   = tid >> 6;
        const int rep  = lane / C_DIM;       // 0..2 active, 3 idle
        const int c    = lane % C_DIM;
        const int kbase = wv * 5;
        float acc[5];
        #pragma unroll
        for (int kk = 0; kk < 5; ++kk) acc[kk] = 0.f;
        for (int j = 0; j < 43; ++j) {
            const int a4 = rep + 3 * j;
            if (rep < 3 && a4 < 128) {
                float4 wc = *(const float4*)&s_w[c][a4 * 4];
                #pragma unroll
                for (int kk = 0; kk < 5; ++kk) {
                    int k = kbase + kk; if (k > 18) k = 18;   // clamp; result discarded
                    float4 cv = *(const float4*)&s_cov[k][a4 * 4];
                    float4 wk = *(const float4*)&s_w[k][a4 * 4];
                    float dx = wc.x - wk.x, dy = wc.y - wk.y;
                    float dz = wc.z - wk.z, dw = wc.w - wk.w;
                    acc[kk] = fmaf(cv.x, dx * dx, acc[kk]);
                    acc[kk] = fmaf(cv.y, dy * dy, acc[kk]);
                    acc[kk] = fmaf(cv.z, dz * dz, acc[kk]);
                    acc[kk] = fmaf(cv.w, dw * dw, acc[kk]);
                }
            }
        }
        #pragma unroll
        for (int kk = 0; kk < 5; ++kk) {
            const int k = kbase + kk;
            float v1 = __shfl(acc[kk], lane + 19);
            float v2 = __shfl(acc[kk], lane + 38);
            if (lane < C_DIM && k < C_DIM) s_S[k * 20 + lane] = ratio * (acc[kk] + v1 + v2);
        }
    }
    __syncthreads();

    // stage D: apply
    const int total4 = N_DIM * C_DIM * (HW / 4);   // 311296
    const int per_n  = C_DIM * (HW / 4);           // 77824
    for (int g = blockIdx.x * 256 + tid; g < total4; g += (int)gridDim.x * 256) {
        const int n   = g / per_n;
        const int rem = g - n * per_n;
        const int c   = rem >> 12;                 // /4096
        const int hw4 = rem & 4095;
        float4 yv = ((const float4*)y)[g];
        int4 lbv = ((const int4*)(labels + n * HW))[hw4];
        float4 r;
        { int l = lbv.x; bool v = (l != 255); int lu = ((unsigned)l < 19u) ? l : 0;
          r.x = yv.x + (v ? 0.5f * s_S[lu * 20 + c] : 0.f); }
        { int l = lbv.y; bool v = (l != 255); int lu = ((unsigned)l < 19u) ? l : 0;
          r.y = yv.y + (v ? 0.5f * s_S[lu * 20 + c] : 0.f); }
        { int l = lbv.z; bool v = (l != 255); int lu = ((unsigned)l < 19u) ? l : 0;
          r.z = yv.z + (v ? 0.5f * s_S[lu * 20 + c] : 0.f); }
        { int l = lbv.w; bool v = (l != 255); int lu = ((unsigned)l < 19u) ? l : 0;
          r.w = yv.w + (v ? 0.5f * s_S[lu * 20 + c] : 0.f); }
        ((float4*)out)[g] = r;
    }
}

// ---------------------------------------------------------------------------
extern "C" void kernel_launch(void* const* d_in, const int* in_sizes, int n_in,
                              void* d_out, int out_size, void* d_ws, size_t ws_size,
                              hipStream_t stream) {
    const float* feat   = (const float*)d_in[0];   // [N,A,H,W]
    const float* y      = (const float*)d_in[1];   // [N,C,H,W]
    const int*   labels = (const int*)d_in[2];     // [N,1,H,W] int32
    const float* weight = (const float*)d_in[3];   // [C,A]
    const float* CoV    = (const float*)d_in[4];   // [C,A]
    const float* Ave    = (const float*)d_in[5];   // [C,A]
    const float* Amount = (const float*)d_in[6];   // [C]
    const float* ratio  = (const float*)d_in[7];   // scalar

    float* out       = (float*)d_out;
    float* ws        = (float*)d_ws;
    float* gsum_part = ws;                 // [4][19][512]
    float* gsq_part  = ws + 4 * CA;        // [4][19][512]
    float* gcnt_part = ws + 8 * CA;        // [4][32]

    reduce_kernel<<<N_DIM * A_DIM, 256, 0, stream>>>(feat, labels, gsum_part, gsq_part, gcnt_part);
    fused_kernel<<<512, 256, 0, stream>>>(gsum_part, gsq_part, gcnt_part, CoV, Ave, Amount,
                                          weight, ratio, y, labels, out);
}